// Round 1
// baseline (910.921 us; speedup 1.0000x reference)
//
#include <hip/hip_runtime.h>

static inline size_t align256(size_t x) { return (x + 255) & ~size_t(255); }

// ---------------- CSR build ----------------

__global__ __launch_bounds__(256) void hist_kernel(const int* __restrict__ row,
                                                   int* __restrict__ cnt, int E) {
  int i = blockIdx.x * blockDim.x + threadIdx.x;
  if (i < E) atomicAdd(&cnt[row[i]], 1);
}

__global__ __launch_bounds__(1024) void exscan_kernel(const int* __restrict__ cnt,
                                                      int* __restrict__ off,
                                                      int* __restrict__ cursor, int n) {
  __shared__ int sh[1024];
  __shared__ int s_carry;
  int t = threadIdx.x;
  if (t == 0) s_carry = 0;
  __syncthreads();
  for (int base = 0; base < n; base += 1024) {
    int idx = base + t;
    int v = (idx < n) ? cnt[idx] : 0;
    sh[t] = v;
    __syncthreads();
    // Hillis-Steele inclusive scan
    for (int o = 1; o < 1024; o <<= 1) {
      int add = (t >= o) ? sh[t - o] : 0;
      __syncthreads();
      sh[t] += add;
      __syncthreads();
    }
    int carry = s_carry;           // safe: last write was before a barrier
    int excl = carry + sh[t] - v;  // exclusive prefix
    if (idx < n) { off[idx] = excl; cursor[idx] = excl; }
    __syncthreads();
    if (t == 1023) s_carry = carry + sh[1023];
    __syncthreads();
  }
  if (t == 0) off[n] = s_carry;
}

__global__ __launch_bounds__(256) void scatter_kernel(const int* __restrict__ row,
                                                      const int* __restrict__ col,
                                                      const float* __restrict__ w,
                                                      int* __restrict__ cursor,
                                                      int* __restrict__ cols_s,
                                                      float* __restrict__ ws_s, int E) {
  int i = blockIdx.x * blockDim.x + threadIdx.x;
  if (i < E) {
    int r = row[i];
    int p = atomicAdd(&cursor[r], 1);
    cols_s[p] = col[i];
    ws_s[p] = w[i];
  }
}

// ---------------- fused 3x linear (x @ W + b) ----------------
// block = 384 threads; each block does 16 rows x 384 output cols.
// thread: cx = t%96 -> 4 consecutive cols inside one of the 3 W's; r4 = t/96 -> 4 rows.

#define LIN_ROWS 16

__global__ __launch_bounds__(384) void linear3_kernel(
    const float* __restrict__ x,
    const float* __restrict__ W0, const float* __restrict__ b0,
    const float* __restrict__ W1, const float* __restrict__ b1,
    const float* __restrict__ W2, const float* __restrict__ b2,
    float* __restrict__ d0, float* __restrict__ d1, float* __restrict__ d2,
    int n) {
  __shared__ float xs[LIN_ROWS][128];
  int row0 = blockIdx.x * LIN_ROWS;
  int t = threadIdx.x;

  for (int i = t; i < LIN_ROWS * 128; i += 384) {
    int r = i >> 7, k = i & 127;
    int gr = row0 + r;
    xs[r][k] = (gr < n) ? x[(size_t)gr * 128 + k] : 0.f;
  }
  __syncthreads();

  int cx = t % 96;
  int r4 = t / 96;          // 0..3
  int wsel = cx / 32;       // which W
  int cc = (cx % 32) * 4;   // col within W (multiple of 4)

  const float* W = (wsel == 0) ? W0 : (wsel == 1) ? W1 : W2;
  const float* b = (wsel == 0) ? b0 : (wsel == 1) ? b1 : b2;
  float4 bb = *(const float4*)&b[cc];

  float acc[4][4];
#pragma unroll
  for (int r = 0; r < 4; ++r) {
    acc[r][0] = bb.x; acc[r][1] = bb.y; acc[r][2] = bb.z; acc[r][3] = bb.w;
  }

#pragma unroll 8
  for (int k = 0; k < 128; ++k) {
    float4 w4 = *(const float4*)&W[k * 128 + cc];
#pragma unroll
    for (int r = 0; r < 4; ++r) {
      float xv = xs[r4 * 4 + r][k];
      acc[r][0] += xv * w4.x;
      acc[r][1] += xv * w4.y;
      acc[r][2] += xv * w4.z;
      acc[r][3] += xv * w4.w;
    }
  }

  float* dst = (wsel == 0) ? d0 : (wsel == 1) ? d1 : d2;
  size_t stride = (wsel == 0) ? 384 : 128;
#pragma unroll
  for (int r = 0; r < 4; ++r) {
    int gr = row0 + r4 * 4 + r;
    if (gr < n) {
      *(float4*)&dst[(size_t)gr * stride + cc] =
          make_float4(acc[r][0], acc[r][1], acc[r][2], acc[r][3]);
    }
  }
}

// ---------------- CSR SpMM: one wave per node, float2 per lane ----------------

__global__ __launch_bounds__(256) void spmm_csr_kernel(
    const float* __restrict__ xin, int in_stride,
    float* __restrict__ xout, int out_stride,
    const int* __restrict__ off, const int* __restrict__ cols,
    const float* __restrict__ wgt, int n) {
  int node = blockIdx.x * 4 + (threadIdx.x >> 6);
  if (node >= n) return;
  int lane = threadIdx.x & 63;
  int s = off[node], e = off[node + 1];

  float a0 = 0.f, a1 = 0.f, c0acc = 0.f, c1acc = 0.f;
  int i = s;
  for (; i + 2 <= e; i += 2) {
    int c0 = cols[i], c1 = cols[i + 1];
    float w0 = wgt[i], w1 = wgt[i + 1];
    float2 v0 = *(const float2*)&xin[(size_t)c0 * in_stride + 2 * lane];
    float2 v1 = *(const float2*)&xin[(size_t)c1 * in_stride + 2 * lane];
    a0 += w0 * v0.x; a1 += w0 * v0.y;
    c0acc += w1 * v1.x; c1acc += w1 * v1.y;
  }
  if (i < e) {
    int c0 = cols[i];
    float w0 = wgt[i];
    float2 v0 = *(const float2*)&xin[(size_t)c0 * in_stride + 2 * lane];
    a0 += w0 * v0.x; a1 += w0 * v0.y;
  }
  *(float2*)&xout[(size_t)node * out_stride + 2 * lane] =
      make_float2(a0 + c0acc, a1 + c1acc);
}

// ---------------- launch ----------------

extern "C" void kernel_launch(void* const* d_in, const int* in_sizes, int n_in,
                              void* d_out, int out_size, void* d_ws, size_t ws_size,
                              hipStream_t stream) {
  const float* x  = (const float*)d_in[0];
  const int*   row = (const int*)d_in[1];
  const int*   col = (const int*)d_in[2];
  const float* ew  = (const float*)d_in[3];
  const float* W0  = (const float*)d_in[4];
  const float* b0  = (const float*)d_in[5];
  const float* W1  = (const float*)d_in[6];
  const float* b1  = (const float*)d_in[7];
  const float* W2  = (const float*)d_in[8];
  const float* b2  = (const float*)d_in[9];
  float* out = (float*)d_out;

  int n = in_sizes[0] / 128;
  int E = in_sizes[1];

  char* p = (char*)d_ws;
  size_t o = 0;
  float* y1 = (float*)(p + o); o = align256(o + (size_t)n * 128 * 4);
  float* y2 = (float*)(p + o); o = align256(o + (size_t)n * 128 * 4);
  int* cnt  = (int*)(p + o);   o = align256(o + (size_t)n * 4);
  int* off  = (int*)(p + o);   o = align256(o + ((size_t)n + 1) * 4);
  int* cur  = (int*)(p + o);   o = align256(o + (size_t)n * 4);
  int* cols_s = (int*)(p + o); o = align256(o + (size_t)E * 4);
  float* ws_s = (float*)(p + o); o = align256(o + (size_t)E * 4);
  (void)ws_size; (void)n_in; (void)out_size;

  // CSR build
  hipMemsetAsync(cnt, 0, (size_t)n * 4, stream);
  hist_kernel<<<(E + 255) / 256, 256, 0, stream>>>(row, cnt, E);
  exscan_kernel<<<1, 1024, 0, stream>>>(cnt, off, cur, n);
  scatter_kernel<<<(E + 255) / 256, 256, 0, stream>>>(row, col, ew, cur, cols_s, ws_s, E);

  // x0 -> out[:,0:128]; y1, y2 -> ws
  linear3_kernel<<<(n + LIN_ROWS - 1) / LIN_ROWS, 384, 0, stream>>>(
      x, W0, b0, W1, b1, W2, b2, out, y1, y2, n);

  // z2 = spmm(y2) -> out[:,128:256] (temporary)
  spmm_csr_kernel<<<(n + 3) / 4, 256, 0, stream>>>(y2, 128, out + 128, 384,
                                                   off, cols_s, ws_s, n);
  // x2 = spmm(z2) -> out[:,256:384]
  spmm_csr_kernel<<<(n + 3) / 4, 256, 0, stream>>>(out + 128, 384, out + 256, 384,
                                                   off, cols_s, ws_s, n);
  // x1 = spmm(y1) -> out[:,128:256] (overwrites temp z2)
  spmm_csr_kernel<<<(n + 3) / 4, 256, 0, stream>>>(y1, 128, out + 128, 384,
                                                   off, cols_s, ws_s, n);
}

// Round 2
// 466.724 us; speedup vs baseline: 1.9517x; 1.9517x over previous
//
#include <hip/hip_runtime.h>

typedef __attribute__((ext_vector_type(8))) short bf16x8;
typedef __attribute__((ext_vector_type(4))) float f32x4;

static inline size_t align256(size_t x) { return (x + 255) & ~size_t(255); }

__device__ inline ushort f2bf(float f) {
  uint u = __float_as_uint(f);
  return (ushort)((u + 0x7FFFu + ((u >> 16) & 1u)) >> 16);  // RNE
}
__device__ inline float bf2f(ushort h) { return __uint_as_float(((uint)h) << 16); }

// ---------------- CSR build ----------------

__global__ __launch_bounds__(256) void hist_kernel(const int* __restrict__ row,
                                                   int* __restrict__ cnt, int E) {
  int i = blockIdx.x * blockDim.x + threadIdx.x;
  if (i < E) atomicAdd(&cnt[row[i]], 1);
}

__global__ __launch_bounds__(1024) void scan1_kernel(const int* __restrict__ cnt,
                                                     int* __restrict__ offp,
                                                     int* __restrict__ bsum, int n) {
  __shared__ int sh[1024];
  int t = threadIdx.x;
  int idx = blockIdx.x * 1024 + t;
  int v = (idx < n) ? cnt[idx] : 0;
  sh[t] = v;
  __syncthreads();
  for (int o = 1; o < 1024; o <<= 1) {
    int add = (t >= o) ? sh[t - o] : 0;
    __syncthreads();
    sh[t] += add;
    __syncthreads();
  }
  if (idx < n) offp[idx] = sh[t] - v;  // block-local exclusive
  if (t == 1023) bsum[blockIdx.x] = sh[1023];
}

__global__ __launch_bounds__(128) void scan2_kernel(int* __restrict__ bsum, int nb) {
  __shared__ int sh[128];
  int t = threadIdx.x;
  int v = (t < nb) ? bsum[t] : 0;
  sh[t] = v;
  __syncthreads();
  for (int o = 1; o < 128; o <<= 1) {
    int add = (t >= o) ? sh[t - o] : 0;
    __syncthreads();
    sh[t] += add;
    __syncthreads();
  }
  if (t < nb) bsum[t] = sh[t] - v;  // exclusive block bases
}

__global__ __launch_bounds__(256) void scan3_kernel(int* __restrict__ offp,
                                                    int* __restrict__ cur,
                                                    const int* __restrict__ bsum,
                                                    int n, int E) {
  int idx = blockIdx.x * 256 + threadIdx.x;
  if (idx < n) {
    int o = offp[idx] + bsum[idx >> 10];
    offp[idx] = o;
    cur[idx] = o;
  }
  if (idx == 0) offp[n] = E;
}

__global__ __launch_bounds__(256) void scatter_kernel(const int* __restrict__ row,
                                                      const int* __restrict__ col,
                                                      const float* __restrict__ w,
                                                      int* __restrict__ cursor,
                                                      int2* __restrict__ es, int E) {
  int i = blockIdx.x * blockDim.x + threadIdx.x;
  if (i < E) {
    int r = row[i];
    int p = atomicAdd(&cursor[r], 1);
    es[p] = make_int2(col[i], __float_as_int(w[i]));
  }
}

// ---------------- W transpose + bf16 convert ----------------
// Wt[mat][c][k] = bf16(W[k][c]); 3 mats of 128x128.

__global__ __launch_bounds__(256) void prep_wt_kernel(const float* __restrict__ W0,
                                                      const float* __restrict__ W1,
                                                      const float* __restrict__ W2,
                                                      ushort* __restrict__ Wt) {
  int i = blockIdx.x * 256 + threadIdx.x;
  if (i >= 3 * 16384) return;
  int mat = i >> 14, r = i & 16383;
  int k = r >> 7, c = r & 127;  // consecutive threads vary c -> coalesced read
  const float* W = (mat == 0) ? W0 : (mat == 1) ? W1 : W2;
  Wt[mat * 16384 + c * 128 + k] = f2bf(W[k * 128 + c]);
}

// ---------------- fused 3x GEMM via MFMA (swapped operands) ----------------
// D' = Wt x^T : A-operand = Wt fragment (16 out-cols x 32 k), B-operand = x
// fragment (32 k x 16 rows). D' mapping: x-row = lane&15, out-col =
// (lane>>4)*4 + reg. 256 threads = 4 waves; wave handles 64 rows x 384 cols.

__global__ __launch_bounds__(256) void gemm3_kernel(
    const float* __restrict__ x, const ushort* __restrict__ Wt,
    const float* __restrict__ b0, const float* __restrict__ b1,
    const float* __restrict__ b2,
    float* __restrict__ out0,      // stride 384 (d_out col 0..127)
    ushort* __restrict__ y1,       // bf16, stride 128
    ushort* __restrict__ y2,       // bf16, stride 128
    int n) {
  int w = threadIdx.x >> 6;
  int l = threadIdx.x & 63;
  int lr = l & 15;   // x-row within tile / Wt-col within tile
  int lg = l >> 4;   // k sub-chunk group
  int rows0 = blockIdx.x * 256 + w * 64;

  // Load + convert x fragments: xf[rowtile][kchunk], 8 bf16 each.
  bf16x8 xf[4][4];
#pragma unroll
  for (int rt = 0; rt < 4; ++rt) {
    int row = rows0 + rt * 16 + lr;
    bool ok = row < n;
    const float* base = x + (size_t)row * 128;
#pragma unroll
    for (int kc = 0; kc < 4; ++kc) {
      float4 a = ok ? *(const float4*)(base + kc * 32 + lg * 8) : make_float4(0, 0, 0, 0);
      float4 c = ok ? *(const float4*)(base + kc * 32 + lg * 8 + 4) : make_float4(0, 0, 0, 0);
      bf16x8 f;
      f[0] = (short)f2bf(a.x); f[1] = (short)f2bf(a.y);
      f[2] = (short)f2bf(a.z); f[3] = (short)f2bf(a.w);
      f[4] = (short)f2bf(c.x); f[5] = (short)f2bf(c.y);
      f[6] = (short)f2bf(c.z); f[7] = (short)f2bf(c.w);
      xf[rt][kc] = f;
    }
  }

  for (int mat = 0; mat < 3; ++mat) {
    const ushort* Wm = Wt + mat * 16384;
    const float* bias = (mat == 0) ? b0 : (mat == 1) ? b1 : b2;
#pragma unroll 1
    for (int ct = 0; ct < 8; ++ct) {
      bf16x8 wf[4];
#pragma unroll
      for (int kc = 0; kc < 4; ++kc)
        wf[kc] = *(const bf16x8*)(Wm + (ct * 16 + lr) * 128 + kc * 32 + lg * 8);
      float4 bb = *(const float4*)(bias + ct * 16 + lg * 4);
      f32x4 acc[4];
#pragma unroll
      for (int rt = 0; rt < 4; ++rt) {
        acc[rt][0] = bb.x; acc[rt][1] = bb.y; acc[rt][2] = bb.z; acc[rt][3] = bb.w;
      }
#pragma unroll
      for (int kc = 0; kc < 4; ++kc)
#pragma unroll
        for (int rt = 0; rt < 4; ++rt)
          acc[rt] = __builtin_amdgcn_mfma_f32_16x16x32_bf16(wf[kc], xf[rt][kc], acc[rt], 0, 0, 0);
#pragma unroll
      for (int rt = 0; rt < 4; ++rt) {
        int row = rows0 + rt * 16 + lr;
        if (row >= n) continue;
        int col = ct * 16 + lg * 4;
        if (mat == 0) {
          *(f32x4*)(out0 + (size_t)row * 384 + col) = acc[rt];
        } else {
          ushort4 h;
          h.x = f2bf(acc[rt][0]); h.y = f2bf(acc[rt][1]);
          h.z = f2bf(acc[rt][2]); h.w = f2bf(acc[rt][3]);
          ushort* Y = (mat == 1) ? y1 : y2;
          *(ushort4*)(Y + (size_t)row * 128 + col) = h;
        }
      }
    }
  }
}

// ---------------- SpMM (CSR, wave per node) ----------------
// dual: x1 = A*y1 (bf16 gather -> fp32 out), z2 = A*y2 (bf16 gather -> fp32 ws)

__global__ __launch_bounds__(256) void spmm_dual_kernel(
    const ushort* __restrict__ y1, const ushort* __restrict__ y2,
    float* __restrict__ o1,        // d_out + 128, stride 384
    float* __restrict__ z2,        // fp32, stride 128
    const int* __restrict__ off, const int2* __restrict__ es, int n) {
  int node = blockIdx.x * 4 + (threadIdx.x >> 6);
  if (node >= n) return;
  int l = threadIdx.x & 63;
  int s = off[node], e = off[node + 1];
  float a0 = 0.f, a1 = 0.f, c0 = 0.f, c1 = 0.f;
  int i = s;
  for (; i + 2 <= e; i += 2) {
    int2 e0 = es[i], e1 = es[i + 1];
    float w0 = __int_as_float(e0.y), w1 = __int_as_float(e1.y);
    uint u10 = *(const uint*)(y1 + (size_t)e0.x * 128 + 2 * l);
    uint u20 = *(const uint*)(y2 + (size_t)e0.x * 128 + 2 * l);
    uint u11 = *(const uint*)(y1 + (size_t)e1.x * 128 + 2 * l);
    uint u21 = *(const uint*)(y2 + (size_t)e1.x * 128 + 2 * l);
    a0 += w0 * bf2f((ushort)u10); a1 += w0 * bf2f((ushort)(u10 >> 16));
    c0 += w0 * bf2f((ushort)u20); c1 += w0 * bf2f((ushort)(u20 >> 16));
    a0 += w1 * bf2f((ushort)u11); a1 += w1 * bf2f((ushort)(u11 >> 16));
    c0 += w1 * bf2f((ushort)u21); c1 += w1 * bf2f((ushort)(u21 >> 16));
  }
  if (i < e) {
    int2 e0 = es[i];
    float w0 = __int_as_float(e0.y);
    uint u10 = *(const uint*)(y1 + (size_t)e0.x * 128 + 2 * l);
    uint u20 = *(const uint*)(y2 + (size_t)e0.x * 128 + 2 * l);
    a0 += w0 * bf2f((ushort)u10); a1 += w0 * bf2f((ushort)(u10 >> 16));
    c0 += w0 * bf2f((ushort)u20); c1 += w0 * bf2f((ushort)(u20 >> 16));
  }
  *(float2*)(o1 + (size_t)node * 384 + 2 * l) = make_float2(a0, a1);
  *(float2*)(z2 + (size_t)node * 128 + 2 * l) = make_float2(c0, c1);
}

// single: x2 = A*z2 (fp32 gather -> fp32 out)
__global__ __launch_bounds__(256) void spmm_single_kernel(
    const float* __restrict__ z2,
    float* __restrict__ o2,        // d_out + 256, stride 384
    const int* __restrict__ off, const int2* __restrict__ es, int n) {
  int node = blockIdx.x * 4 + (threadIdx.x >> 6);
  if (node >= n) return;
  int l = threadIdx.x & 63;
  int s = off[node], e = off[node + 1];
  float a0 = 0.f, a1 = 0.f, b0 = 0.f, b1 = 0.f;
  int i = s;
  for (; i + 2 <= e; i += 2) {
    int2 e0 = es[i], e1 = es[i + 1];
    float w0 = __int_as_float(e0.y), w1 = __int_as_float(e1.y);
    float2 v0 = *(const float2*)(z2 + (size_t)e0.x * 128 + 2 * l);
    float2 v1 = *(const float2*)(z2 + (size_t)e1.x * 128 + 2 * l);
    a0 += w0 * v0.x; a1 += w0 * v0.y;
    b0 += w1 * v1.x; b1 += w1 * v1.y;
  }
  if (i < e) {
    int2 e0 = es[i];
    float w0 = __int_as_float(e0.y);
    float2 v0 = *(const float2*)(z2 + (size_t)e0.x * 128 + 2 * l);
    a0 += w0 * v0.x; a1 += w0 * v0.y;
  }
  *(float2*)(o2 + (size_t)node * 384 + 2 * l) = make_float2(a0 + b0, a1 + b1);
}

// ---------------- launch ----------------

extern "C" void kernel_launch(void* const* d_in, const int* in_sizes, int n_in,
                              void* d_out, int out_size, void* d_ws, size_t ws_size,
                              hipStream_t stream) {
  const float* x   = (const float*)d_in[0];
  const int*   row = (const int*)d_in[1];
  const int*   col = (const int*)d_in[2];
  const float* ew  = (const float*)d_in[3];
  const float* W0  = (const float*)d_in[4];
  const float* b0  = (const float*)d_in[5];
  const float* W1  = (const float*)d_in[6];
  const float* b1  = (const float*)d_in[7];
  const float* W2  = (const float*)d_in[8];
  const float* b2  = (const float*)d_in[9];
  float* out = (float*)d_out;

  int n = in_sizes[0] / 128;
  int E = in_sizes[1];

  char* p = (char*)d_ws;
  size_t o = 0;
  ushort* y1 = (ushort*)(p + o); o = align256(o + (size_t)n * 128 * 2);
  ushort* y2 = (ushort*)(p + o); o = align256(o + (size_t)n * 128 * 2);
  float*  z2 = (float*)(p + o);  o = align256(o + (size_t)n * 128 * 4);
  ushort* Wt = (ushort*)(p + o); o = align256(o + (size_t)3 * 16384 * 2);
  int* cnt   = (int*)(p + o);    o = align256(o + (size_t)n * 4);
  int* offp  = (int*)(p + o);    o = align256(o + ((size_t)n + 1) * 4);
  int* cur   = (int*)(p + o);    o = align256(o + (size_t)n * 4);
  int* bsum  = (int*)(p + o);    o = align256(o + 128 * 4);
  int2* es   = (int2*)(p + o);   o = align256(o + (size_t)E * 8);
  (void)ws_size; (void)n_in; (void)out_size;

  int nb = (n + 1023) / 1024;

  // CSR build
  hipMemsetAsync(cnt, 0, (size_t)n * 4, stream);
  hist_kernel<<<(E + 255) / 256, 256, 0, stream>>>(row, cnt, E);
  scan1_kernel<<<nb, 1024, 0, stream>>>(cnt, offp, bsum, n);
  scan2_kernel<<<1, 128, 0, stream>>>(bsum, nb);
  scan3_kernel<<<(n + 255) / 256, 256, 0, stream>>>(offp, cur, bsum, n, E);
  scatter_kernel<<<(E + 255) / 256, 256, 0, stream>>>(row, col, ew, cur, es, E);

  // Weights -> bf16 transposed
  prep_wt_kernel<<<192, 256, 0, stream>>>(W0, W1, W2, Wt);

  // Fused GEMMs: out0 fp32, y1/y2 bf16
  gemm3_kernel<<<(n + 255) / 256, 256, 0, stream>>>(x, Wt, b0, b1, b2,
                                                    out, y1, y2, n);

  // x1 -> out[:,128:256], z2 (fp32) -> ws
  spmm_dual_kernel<<<(n + 3) / 4, 256, 0, stream>>>(y1, y2, out + 128, z2,
                                                    offp, es, n);
  // x2 = A*z2 -> out[:,256:384]
  spmm_single_kernel<<<(n + 3) / 4, 256, 0, stream>>>(z2, out + 256,
                                                      offp, es, n);
}

// Round 3
// 403.489 us; speedup vs baseline: 2.2576x; 1.1567x over previous
//
#include <hip/hip_runtime.h>

typedef __attribute__((ext_vector_type(8))) short bf16x8;
typedef __attribute__((ext_vector_type(4))) float f32x4;

static inline size_t align256(size_t x) { return (x + 255) & ~size_t(255); }

__device__ inline ushort f2bf(float f) {
  uint u = __float_as_uint(f);
  return (ushort)((u + 0x7FFFu + ((u >> 16) & 1u)) >> 16);  // RNE
}
__device__ inline float bf2f(ushort h) { return __uint_as_float(((uint)h) << 16); }

// ---------------- CSR build ----------------

__global__ __launch_bounds__(256) void hist_kernel(const int* __restrict__ row,
                                                   int* __restrict__ cnt, int E) {
  int i = blockIdx.x * blockDim.x + threadIdx.x;
  if (i < E) atomicAdd(&cnt[row[i]], 1);
}

__global__ __launch_bounds__(1024) void scan1_kernel(const int* __restrict__ cnt,
                                                     int* __restrict__ offp,
                                                     int* __restrict__ bsum, int n) {
  __shared__ int sh[1024];
  int t = threadIdx.x;
  int idx = blockIdx.x * 1024 + t;
  int v = (idx < n) ? cnt[idx] : 0;
  sh[t] = v;
  __syncthreads();
  for (int o = 1; o < 1024; o <<= 1) {
    int add = (t >= o) ? sh[t - o] : 0;
    __syncthreads();
    sh[t] += add;
    __syncthreads();
  }
  if (idx < n) offp[idx] = sh[t] - v;  // block-local exclusive
  if (t == 1023) bsum[blockIdx.x] = sh[1023];
}

__global__ __launch_bounds__(128) void scan2_kernel(int* __restrict__ bsum, int nb) {
  __shared__ int sh[128];
  int t = threadIdx.x;
  int v = (t < nb) ? bsum[t] : 0;
  sh[t] = v;
  __syncthreads();
  for (int o = 1; o < 128; o <<= 1) {
    int add = (t >= o) ? sh[t - o] : 0;
    __syncthreads();
    sh[t] += add;
    __syncthreads();
  }
  if (t < nb) bsum[t] = sh[t] - v;  // exclusive block bases
}

__global__ __launch_bounds__(256) void scan3_kernel(int* __restrict__ offp,
                                                    int* __restrict__ cur,
                                                    const int* __restrict__ bsum,
                                                    int n, int E) {
  int idx = blockIdx.x * 256 + threadIdx.x;
  if (idx < n) {
    int o = offp[idx] + bsum[idx >> 10];
    offp[idx] = o;
    cur[idx] = o;
  }
  if (idx == 0) offp[n] = E;
}

__global__ __launch_bounds__(256) void scatter_kernel(const int* __restrict__ row,
                                                      const int* __restrict__ col,
                                                      const float* __restrict__ w,
                                                      int* __restrict__ cursor,
                                                      int2* __restrict__ es, int E) {
  int i = blockIdx.x * blockDim.x + threadIdx.x;
  if (i < E) {
    int r = row[i];
    int p = atomicAdd(&cursor[r], 1);
    es[p] = make_int2(col[i], __float_as_int(w[i]));
  }
}

// ---------------- W transpose + bf16 convert ----------------

__global__ __launch_bounds__(256) void prep_wt_kernel(const float* __restrict__ W0,
                                                      const float* __restrict__ W1,
                                                      const float* __restrict__ W2,
                                                      ushort* __restrict__ Wt) {
  int i = blockIdx.x * 256 + threadIdx.x;
  if (i >= 3 * 16384) return;
  int mat = i >> 14, r = i & 16383;
  int k = r >> 7, c = r & 127;
  const float* W = (mat == 0) ? W0 : (mat == 1) ? W1 : W2;
  Wt[mat * 16384 + c * 128 + k] = f2bf(W[k * 128 + c]);
}

// ---------------- fused 3x GEMM via MFMA (swapped operands) ----------------
// y12 layout: node stride 256 ushorts; [0:128) = y1 row, [128:256) = y2 row.

__global__ __launch_bounds__(256) void gemm3_kernel(
    const float* __restrict__ x, const ushort* __restrict__ Wt,
    const float* __restrict__ b0, const float* __restrict__ b1,
    const float* __restrict__ b2,
    float* __restrict__ out0,      // stride 384 (d_out col 0..127)
    ushort* __restrict__ y12,      // bf16 co-located y1|y2, stride 256
    int n) {
  int w = threadIdx.x >> 6;
  int l = threadIdx.x & 63;
  int lr = l & 15;
  int lg = l >> 4;
  int rows0 = blockIdx.x * 256 + w * 64;

  bf16x8 xf[4][4];
#pragma unroll
  for (int rt = 0; rt < 4; ++rt) {
    int row = rows0 + rt * 16 + lr;
    bool ok = row < n;
    const float* base = x + (size_t)row * 128;
#pragma unroll
    for (int kc = 0; kc < 4; ++kc) {
      float4 a = ok ? *(const float4*)(base + kc * 32 + lg * 8) : make_float4(0, 0, 0, 0);
      float4 c = ok ? *(const float4*)(base + kc * 32 + lg * 8 + 4) : make_float4(0, 0, 0, 0);
      bf16x8 f;
      f[0] = (short)f2bf(a.x); f[1] = (short)f2bf(a.y);
      f[2] = (short)f2bf(a.z); f[3] = (short)f2bf(a.w);
      f[4] = (short)f2bf(c.x); f[5] = (short)f2bf(c.y);
      f[6] = (short)f2bf(c.z); f[7] = (short)f2bf(c.w);
      xf[rt][kc] = f;
    }
  }

  for (int mat = 0; mat < 3; ++mat) {
    const ushort* Wm = Wt + mat * 16384;
    const float* bias = (mat == 0) ? b0 : (mat == 1) ? b1 : b2;
#pragma unroll 1
    for (int ct = 0; ct < 8; ++ct) {
      bf16x8 wf[4];
#pragma unroll
      for (int kc = 0; kc < 4; ++kc)
        wf[kc] = *(const bf16x8*)(Wm + (ct * 16 + lr) * 128 + kc * 32 + lg * 8);
      float4 bb = *(const float4*)(bias + ct * 16 + lg * 4);
      f32x4 acc[4];
#pragma unroll
      for (int rt = 0; rt < 4; ++rt) {
        acc[rt][0] = bb.x; acc[rt][1] = bb.y; acc[rt][2] = bb.z; acc[rt][3] = bb.w;
      }
#pragma unroll
      for (int kc = 0; kc < 4; ++kc)
#pragma unroll
        for (int rt = 0; rt < 4; ++rt)
          acc[rt] = __builtin_amdgcn_mfma_f32_16x16x32_bf16(wf[kc], xf[rt][kc], acc[rt], 0, 0, 0);
#pragma unroll
      for (int rt = 0; rt < 4; ++rt) {
        int row = rows0 + rt * 16 + lr;
        if (row >= n) continue;
        int col = ct * 16 + lg * 4;
        if (mat == 0) {
          *(f32x4*)(out0 + (size_t)row * 384 + col) = acc[rt];
        } else {
          ushort4 h;
          h.x = f2bf(acc[rt][0]); h.y = f2bf(acc[rt][1]);
          h.z = f2bf(acc[rt][2]); h.w = f2bf(acc[rt][3]);
          ushort* Y = y12 + (size_t)row * 256 + ((mat == 2) ? 128 : 0);
          *(ushort4*)(Y + col) = h;
        }
      }
    }
  }
}

// ---------------- SpMM (CSR, wave per node) ----------------
// dual: x1 = A*y1 -> fp32 out, z2 = A*y2 -> bf16 ws. y12 co-located rows.

__global__ __launch_bounds__(256) void spmm_dual_kernel(
    const ushort* __restrict__ y12,
    float* __restrict__ o1,        // d_out + 128, stride 384
    ushort* __restrict__ z2,       // bf16, stride 128
    const int* __restrict__ off, const int2* __restrict__ es, int n) {
  int node = blockIdx.x * 4 + (threadIdx.x >> 6);
  if (node >= n) return;
  int l = threadIdx.x & 63;
  int s = off[node], e = off[node + 1];
  float a0 = 0.f, a1 = 0.f, c0 = 0.f, c1 = 0.f;
  int i = s;
  for (; i + 4 <= e; i += 4) {
    int2 ed[4];
    ed[0] = es[i]; ed[1] = es[i + 1]; ed[2] = es[i + 2]; ed[3] = es[i + 3];
    uint u1[4], u2[4];
#pragma unroll
    for (int j = 0; j < 4; ++j) {
      const ushort* base = y12 + (size_t)ed[j].x * 256;
      u1[j] = *(const uint*)(base + 2 * l);
      u2[j] = *(const uint*)(base + 128 + 2 * l);
    }
#pragma unroll
    for (int j = 0; j < 4; ++j) {
      float w = __int_as_float(ed[j].y);
      a0 += w * bf2f((ushort)u1[j]); a1 += w * bf2f((ushort)(u1[j] >> 16));
      c0 += w * bf2f((ushort)u2[j]); c1 += w * bf2f((ushort)(u2[j] >> 16));
    }
  }
  for (; i < e; ++i) {
    int2 e0 = es[i];
    float w = __int_as_float(e0.y);
    const ushort* base = y12 + (size_t)e0.x * 256;
    uint u1 = *(const uint*)(base + 2 * l);
    uint u2 = *(const uint*)(base + 128 + 2 * l);
    a0 += w * bf2f((ushort)u1); a1 += w * bf2f((ushort)(u1 >> 16));
    c0 += w * bf2f((ushort)u2); c1 += w * bf2f((ushort)(u2 >> 16));
  }
  *(float2*)(o1 + (size_t)node * 384 + 2 * l) = make_float2(a0, a1);
  uint z = (uint)f2bf(c0) | ((uint)f2bf(c1) << 16);
  *(uint*)(z2 + (size_t)node * 128 + 2 * l) = z;
}

// single: x2 = A*z2 (bf16 gather -> fp32 out)
__global__ __launch_bounds__(256) void spmm_single_kernel(
    const ushort* __restrict__ z2,
    float* __restrict__ o2,        // d_out + 256, stride 384
    const int* __restrict__ off, const int2* __restrict__ es, int n) {
  int node = blockIdx.x * 4 + (threadIdx.x >> 6);
  if (node >= n) return;
  int l = threadIdx.x & 63;
  int s = off[node], e = off[node + 1];
  float a0 = 0.f, a1 = 0.f;
  int i = s;
  for (; i + 4 <= e; i += 4) {
    int2 ed[4];
    ed[0] = es[i]; ed[1] = es[i + 1]; ed[2] = es[i + 2]; ed[3] = es[i + 3];
    uint u[4];
#pragma unroll
    for (int j = 0; j < 4; ++j)
      u[j] = *(const uint*)(z2 + (size_t)ed[j].x * 128 + 2 * l);
#pragma unroll
    for (int j = 0; j < 4; ++j) {
      float w = __int_as_float(ed[j].y);
      a0 += w * bf2f((ushort)u[j]); a1 += w * bf2f((ushort)(u[j] >> 16));
    }
  }
  for (; i < e; ++i) {
    int2 e0 = es[i];
    float w = __int_as_float(e0.y);
    uint u = *(const uint*)(z2 + (size_t)e0.x * 128 + 2 * l);
    a0 += w * bf2f((ushort)u); a1 += w * bf2f((ushort)(u >> 16));
  }
  *(float2*)(o2 + (size_t)node * 384 + 2 * l) = make_float2(a0, a1);
}

// ---------------- launch ----------------

extern "C" void kernel_launch(void* const* d_in, const int* in_sizes, int n_in,
                              void* d_out, int out_size, void* d_ws, size_t ws_size,
                              hipStream_t stream) {
  const float* x   = (const float*)d_in[0];
  const int*   row = (const int*)d_in[1];
  const int*   col = (const int*)d_in[2];
  const float* ew  = (const float*)d_in[3];
  const float* W0  = (const float*)d_in[4];
  const float* b0  = (const float*)d_in[5];
  const float* W1  = (const float*)d_in[6];
  const float* b1  = (const float*)d_in[7];
  const float* W2  = (const float*)d_in[8];
  const float* b2  = (const float*)d_in[9];
  float* out = (float*)d_out;

  int n = in_sizes[0] / 128;
  int E = in_sizes[1];

  char* p = (char*)d_ws;
  size_t o = 0;
  ushort* y12 = (ushort*)(p + o); o = align256(o + (size_t)n * 256 * 2);
  ushort* z2  = (ushort*)(p + o); o = align256(o + (size_t)n * 128 * 2);
  ushort* Wt  = (ushort*)(p + o); o = align256(o + (size_t)3 * 16384 * 2);
  int* cnt    = (int*)(p + o);    o = align256(o + (size_t)n * 4);
  int* offp   = (int*)(p + o);    o = align256(o + ((size_t)n + 1) * 4);
  int* cur    = (int*)(p + o);    o = align256(o + (size_t)n * 4);
  int* bsum   = (int*)(p + o);    o = align256(o + 128 * 4);
  int2* es    = (int2*)(p + o);   o = align256(o + (size_t)E * 8);
  (void)ws_size; (void)n_in; (void)out_size;

  int nb = (n + 1023) / 1024;

  // CSR build
  hipMemsetAsync(cnt, 0, (size_t)n * 4, stream);
  hist_kernel<<<(E + 255) / 256, 256, 0, stream>>>(row, cnt, E);
  scan1_kernel<<<nb, 1024, 0, stream>>>(cnt, offp, bsum, n);
  scan2_kernel<<<1, 128, 0, stream>>>(bsum, nb);
  scan3_kernel<<<(n + 255) / 256, 256, 0, stream>>>(offp, cur, bsum, n, E);
  scatter_kernel<<<(E + 255) / 256, 256, 0, stream>>>(row, col, ew, cur, es, E);

  // Weights -> bf16 transposed
  prep_wt_kernel<<<192, 256, 0, stream>>>(W0, W1, W2, Wt);

  // Fused GEMMs: out0 fp32, y12 bf16
  gemm3_kernel<<<(n + 255) / 256, 256, 0, stream>>>(x, Wt, b0, b1, b2,
                                                    out, y12, n);

  // x1 -> out[:,128:256], z2 (bf16) -> ws
  spmm_dual_kernel<<<(n + 3) / 4, 256, 0, stream>>>(y12, out + 128, z2,
                                                    offp, es, n);
  // x2 = A*z2 -> out[:,256:384]
  spmm_single_kernel<<<(n + 3) / 4, 256, 0, stream>>>(z2, out + 256,
                                                      offp, es, n);
}

// Round 4
// 334.716 us; speedup vs baseline: 2.7215x; 1.2055x over previous
//
#include <hip/hip_runtime.h>

typedef __attribute__((ext_vector_type(8))) short bf16x8;
typedef __attribute__((ext_vector_type(4))) float f32x4;

static inline size_t align256(size_t x) { return (x + 255) & ~size_t(255); }

__device__ inline ushort f2bf(float f) {
  uint u = __float_as_uint(f);
  return (ushort)((u + 0x7FFFu + ((u >> 16) & 1u)) >> 16);  // RNE
}
__device__ inline float bf2f(ushort h) { return __uint_as_float(((uint)h) << 16); }

#define BW_SHIFT 8            // 256 nodes per bucket
#define NBUCK_MAX 512
#define CHUNK 8192
#define PH2_CAP 6144          // max staged edges per bucket (48 KB LDS)

// ---------------- CSR build: two-phase binned counting sort ----------------

// (a) global bucket histogram via LDS
__global__ __launch_bounds__(256) void bucket_hist(const int* __restrict__ row,
                                                   int* __restrict__ bcnt, int E) {
  __shared__ int h[NBUCK_MAX];
  for (int i = threadIdx.x; i < NBUCK_MAX; i += 256) h[i] = 0;
  __syncthreads();
  for (int i = blockIdx.x * 256 + threadIdx.x; i < E; i += gridDim.x * 256)
    atomicAdd(&h[row[i] >> BW_SHIFT], 1);
  __syncthreads();
  for (int i = threadIdx.x; i < NBUCK_MAX; i += 256)
    if (h[i]) atomicAdd(&bcnt[i], h[i]);
}

// (b) scan bucket counts -> boff, init gcur; set offp[n]=E
__global__ __launch_bounds__(NBUCK_MAX) void bucket_scan(const int* __restrict__ bcnt,
                                                         int* __restrict__ boff,
                                                         int* __restrict__ gcur,
                                                         int* __restrict__ offp,
                                                         int E, int n) {
  __shared__ int sh[NBUCK_MAX];
  int t = threadIdx.x;
  int v = bcnt[t];
  sh[t] = v;
  __syncthreads();
  for (int o = 1; o < NBUCK_MAX; o <<= 1) {
    int a = (t >= o) ? sh[t - o] : 0;
    __syncthreads();
    sh[t] += a;
    __syncthreads();
  }
  int excl = sh[t] - v;
  boff[t] = excl;
  gcur[t] = excl;
  if (t == NBUCK_MAX - 1) boff[NBUCK_MAX] = E;
  if (t == 0) offp[n] = E;
}

// (c) binned scatter: per-chunk LDS counts -> per-bucket run reservation ->
// packed (row_lo<<17|col, w) records written to contiguous runs.
__global__ __launch_bounds__(256) void bin_scatter(const int* __restrict__ row,
                                                   const int* __restrict__ col,
                                                   const float* __restrict__ w,
                                                   int* __restrict__ gcur,
                                                   int2* __restrict__ es_tmp, int E) {
  __shared__ int lh[NBUCK_MAX];
  __shared__ int lbase[NBUCK_MAX];
  int c0 = blockIdx.x * CHUNK;
  int c1 = min(c0 + CHUNK, E);
  for (int i = threadIdx.x; i < NBUCK_MAX; i += 256) lh[i] = 0;
  __syncthreads();
  for (int i = c0 + threadIdx.x; i < c1; i += 256)
    atomicAdd(&lh[row[i] >> BW_SHIFT], 1);
  __syncthreads();
  for (int i = threadIdx.x; i < NBUCK_MAX; i += 256) {
    int c = lh[i];
    lbase[i] = c ? atomicAdd(&gcur[i], c) : 0;
    lh[i] = 0;
  }
  __syncthreads();
  for (int i = c0 + threadIdx.x; i < c1; i += 256) {
    int r = row[i];
    int b = r >> BW_SHIFT;
    int pos = lbase[b] + atomicAdd(&lh[b], 1);
    es_tmp[pos] = make_int2(((r & 255) << 17) | col[i], __float_as_int(w[i]));
  }
}

// (d) per-bucket node sort: LDS stage + 256-node hist/scan -> offp + sorted es
__global__ __launch_bounds__(256) void bucket_sort(const int2* __restrict__ es_tmp,
                                                   const int* __restrict__ boff,
                                                   int2* __restrict__ es,
                                                   int* __restrict__ offp, int n) {
  __shared__ int2 ebuf[PH2_CAP];
  __shared__ int lh[256];
  __shared__ int lex[256];
  int b = blockIdx.x;
  int base = boff[b], cnt = boff[b + 1] - base;
  int t = threadIdx.x;
  bool fits = (cnt <= PH2_CAP);
  lh[t] = 0;
  __syncthreads();
  for (int i = t; i < cnt; i += 256) {
    int2 ed = es_tmp[base + i];
    if (fits) ebuf[i] = ed;
    atomicAdd(&lh[(ed.x >> 17) & 255], 1);
  }
  __syncthreads();
  int v = lh[t];
  lex[t] = v;
  __syncthreads();
  for (int o = 1; o < 256; o <<= 1) {
    int a = (t >= o) ? lex[t - o] : 0;
    __syncthreads();
    lex[t] += a;
    __syncthreads();
  }
  int excl = lex[t] - v;
  int node = (b << BW_SHIFT) + t;
  if (node < n) offp[node] = base + excl;
  __syncthreads();
  lh[t] = excl;  // bucket-local cursor
  __syncthreads();
  for (int i = t; i < cnt; i += 256) {
    int2 ed = fits ? ebuf[i] : es_tmp[base + i];
    int nl = (ed.x >> 17) & 255;
    int pos = base + atomicAdd(&lh[nl], 1);
    es[pos] = make_int2(ed.x & 0x1FFFF, ed.y);
  }
}

// ---------------- W transpose + bf16 convert ----------------

__global__ __launch_bounds__(256) void prep_wt_kernel(const float* __restrict__ W0,
                                                      const float* __restrict__ W1,
                                                      const float* __restrict__ W2,
                                                      ushort* __restrict__ Wt) {
  int i = blockIdx.x * 256 + threadIdx.x;
  if (i >= 3 * 16384) return;
  int mat = i >> 14, r = i & 16383;
  int k = r >> 7, c = r & 127;
  const float* W = (mat == 0) ? W0 : (mat == 1) ? W1 : W2;
  Wt[mat * 16384 + c * 128 + k] = f2bf(W[k * 128 + c]);
}

// ---------------- fused 3x GEMM via MFMA (swapped operands) ----------------
// y12 layout: node stride 256 ushorts; [0:128) = y1 row, [128:256) = y2 row.

__global__ __launch_bounds__(256) void gemm3_kernel(
    const float* __restrict__ x, const ushort* __restrict__ Wt,
    const float* __restrict__ b0, const float* __restrict__ b1,
    const float* __restrict__ b2,
    float* __restrict__ out0,      // stride 384 (d_out col 0..127)
    ushort* __restrict__ y12,      // bf16 co-located y1|y2, stride 256
    int n) {
  int w = threadIdx.x >> 6;
  int l = threadIdx.x & 63;
  int lr = l & 15;
  int lg = l >> 4;
  int rows0 = blockIdx.x * 256 + w * 64;

  bf16x8 xf[4][4];
#pragma unroll
  for (int rt = 0; rt < 4; ++rt) {
    int row = rows0 + rt * 16 + lr;
    bool ok = row < n;
    const float* base = x + (size_t)row * 128;
#pragma unroll
    for (int kc = 0; kc < 4; ++kc) {
      float4 a = ok ? *(const float4*)(base + kc * 32 + lg * 8) : make_float4(0, 0, 0, 0);
      float4 c = ok ? *(const float4*)(base + kc * 32 + lg * 8 + 4) : make_float4(0, 0, 0, 0);
      bf16x8 f;
      f[0] = (short)f2bf(a.x); f[1] = (short)f2bf(a.y);
      f[2] = (short)f2bf(a.z); f[3] = (short)f2bf(a.w);
      f[4] = (short)f2bf(c.x); f[5] = (short)f2bf(c.y);
      f[6] = (short)f2bf(c.z); f[7] = (short)f2bf(c.w);
      xf[rt][kc] = f;
    }
  }

  for (int mat = 0; mat < 3; ++mat) {
    const ushort* Wm = Wt + mat * 16384;
    const float* bias = (mat == 0) ? b0 : (mat == 1) ? b1 : b2;
#pragma unroll 1
    for (int ct = 0; ct < 8; ++ct) {
      bf16x8 wf[4];
#pragma unroll
      for (int kc = 0; kc < 4; ++kc)
        wf[kc] = *(const bf16x8*)(Wm + (ct * 16 + lr) * 128 + kc * 32 + lg * 8);
      float4 bb = *(const float4*)(bias + ct * 16 + lg * 4);
      f32x4 acc[4];
#pragma unroll
      for (int rt = 0; rt < 4; ++rt) {
        acc[rt][0] = bb.x; acc[rt][1] = bb.y; acc[rt][2] = bb.z; acc[rt][3] = bb.w;
      }
#pragma unroll
      for (int kc = 0; kc < 4; ++kc)
#pragma unroll
        for (int rt = 0; rt < 4; ++rt)
          acc[rt] = __builtin_amdgcn_mfma_f32_16x16x32_bf16(wf[kc], xf[rt][kc], acc[rt], 0, 0, 0);
#pragma unroll
      for (int rt = 0; rt < 4; ++rt) {
        int row = rows0 + rt * 16 + lr;
        if (row >= n) continue;
        int col = ct * 16 + lg * 4;
        if (mat == 0) {
          *(f32x4*)(out0 + (size_t)row * 384 + col) = acc[rt];
        } else {
          ushort4 h;
          h.x = f2bf(acc[rt][0]); h.y = f2bf(acc[rt][1]);
          h.z = f2bf(acc[rt][2]); h.w = f2bf(acc[rt][3]);
          ushort* Y = y12 + (size_t)row * 256 + ((mat == 2) ? 128 : 0);
          *(ushort4*)(Y + col) = h;
        }
      }
    }
  }
}

// ---------------- SpMM (CSR, wave per node) ----------------

__global__ __launch_bounds__(256) void spmm_dual_kernel(
    const ushort* __restrict__ y12,
    float* __restrict__ o1,        // d_out + 128, stride 384
    ushort* __restrict__ z2,       // bf16, stride 128
    const int* __restrict__ off, const int2* __restrict__ es, int n) {
  int node = blockIdx.x * 4 + (threadIdx.x >> 6);
  if (node >= n) return;
  int l = threadIdx.x & 63;
  int s = off[node], e = off[node + 1];
  float a0 = 0.f, a1 = 0.f, c0 = 0.f, c1 = 0.f;
  int i = s;
  for (; i + 4 <= e; i += 4) {
    int2 ed[4];
    ed[0] = es[i]; ed[1] = es[i + 1]; ed[2] = es[i + 2]; ed[3] = es[i + 3];
    uint u1[4], u2[4];
#pragma unroll
    for (int j = 0; j < 4; ++j) {
      const ushort* base = y12 + (size_t)ed[j].x * 256;
      u1[j] = *(const uint*)(base + 2 * l);
      u2[j] = *(const uint*)(base + 128 + 2 * l);
    }
#pragma unroll
    for (int j = 0; j < 4; ++j) {
      float w = __int_as_float(ed[j].y);
      a0 += w * bf2f((ushort)u1[j]); a1 += w * bf2f((ushort)(u1[j] >> 16));
      c0 += w * bf2f((ushort)u2[j]); c1 += w * bf2f((ushort)(u2[j] >> 16));
    }
  }
  for (; i < e; ++i) {
    int2 e0 = es[i];
    float w = __int_as_float(e0.y);
    const ushort* base = y12 + (size_t)e0.x * 256;
    uint u1 = *(const uint*)(base + 2 * l);
    uint u2 = *(const uint*)(base + 128 + 2 * l);
    a0 += w * bf2f((ushort)u1); a1 += w * bf2f((ushort)(u1 >> 16));
    c0 += w * bf2f((ushort)u2); c1 += w * bf2f((ushort)(u2 >> 16));
  }
  *(float2*)(o1 + (size_t)node * 384 + 2 * l) = make_float2(a0, a1);
  uint z = (uint)f2bf(c0) | ((uint)f2bf(c1) << 16);
  *(uint*)(z2 + (size_t)node * 128 + 2 * l) = z;
}

__global__ __launch_bounds__(256) void spmm_single_kernel(
    const ushort* __restrict__ z2,
    float* __restrict__ o2,        // d_out + 256, stride 384
    const int* __restrict__ off, const int2* __restrict__ es, int n) {
  int node = blockIdx.x * 4 + (threadIdx.x >> 6);
  if (node >= n) return;
  int l = threadIdx.x & 63;
  int s = off[node], e = off[node + 1];
  float a0 = 0.f, a1 = 0.f;
  int i = s;
  for (; i + 4 <= e; i += 4) {
    int2 ed[4];
    ed[0] = es[i]; ed[1] = es[i + 1]; ed[2] = es[i + 2]; ed[3] = es[i + 3];
    uint u[4];
#pragma unroll
    for (int j = 0; j < 4; ++j)
      u[j] = *(const uint*)(z2 + (size_t)ed[j].x * 128 + 2 * l);
#pragma unroll
    for (int j = 0; j < 4; ++j) {
      float w = __int_as_float(ed[j].y);
      a0 += w * bf2f((ushort)u[j]); a1 += w * bf2f((ushort)(u[j] >> 16));
    }
  }
  for (; i < e; ++i) {
    int2 e0 = es[i];
    float w = __int_as_float(e0.y);
    uint u = *(const uint*)(z2 + (size_t)e0.x * 128 + 2 * l);
    a0 += w * bf2f((ushort)u); a1 += w * bf2f((ushort)(u >> 16));
  }
  *(float2*)(o2 + (size_t)node * 384 + 2 * l) = make_float2(a0, a1);
}

// ---------------- launch ----------------

extern "C" void kernel_launch(void* const* d_in, const int* in_sizes, int n_in,
                              void* d_out, int out_size, void* d_ws, size_t ws_size,
                              hipStream_t stream) {
  const float* x   = (const float*)d_in[0];
  const int*   row = (const int*)d_in[1];
  const int*   col = (const int*)d_in[2];
  const float* ew  = (const float*)d_in[3];
  const float* W0  = (const float*)d_in[4];
  const float* b0  = (const float*)d_in[5];
  const float* W1  = (const float*)d_in[6];
  const float* b1  = (const float*)d_in[7];
  const float* W2  = (const float*)d_in[8];
  const float* b2  = (const float*)d_in[9];
  float* out = (float*)d_out;

  int n = in_sizes[0] / 128;
  int E = in_sizes[1];

  char* p = (char*)d_ws;
  size_t o = 0;
  ushort* y12 = (ushort*)(p + o); o = align256(o + (size_t)n * 256 * 2);
  ushort* z2  = (ushort*)(p + o); o = align256(o + (size_t)n * 128 * 2);
  ushort* Wt  = (ushort*)(p + o); o = align256(o + (size_t)3 * 16384 * 2);
  int* bcnt   = (int*)(p + o);    o = align256(o + (size_t)NBUCK_MAX * 4);
  int* boff   = (int*)(p + o);    o = align256(o + (size_t)(NBUCK_MAX + 1) * 4);
  int* gcur   = (int*)(p + o);    o = align256(o + (size_t)NBUCK_MAX * 4);
  int* offp   = (int*)(p + o);    o = align256(o + ((size_t)n + 1) * 4);
  int2* es_t  = (int2*)(p + o);   o = align256(o + (size_t)E * 8);
  int2* es    = (int2*)(p + o);   o = align256(o + (size_t)E * 8);
  (void)ws_size; (void)n_in; (void)out_size;

  int nbuck = (n + 255) >> 8;

  // CSR build (binned counting sort)
  hipMemsetAsync(bcnt, 0, (size_t)NBUCK_MAX * 4, stream);
  bucket_hist<<<1024, 256, 0, stream>>>(row, bcnt, E);
  bucket_scan<<<1, NBUCK_MAX, 0, stream>>>(bcnt, boff, gcur, offp, E, n);
  bin_scatter<<<(E + CHUNK - 1) / CHUNK, 256, 0, stream>>>(row, col, ew, gcur, es_t, E);
  bucket_sort<<<nbuck, 256, 0, stream>>>(es_t, boff, es, offp, n);

  // Weights -> bf16 transposed
  prep_wt_kernel<<<192, 256, 0, stream>>>(W0, W1, W2, Wt);

  // Fused GEMMs: out0 fp32, y12 bf16
  gemm3_kernel<<<(n + 255) / 256, 256, 0, stream>>>(x, Wt, b0, b1, b2,
                                                    out, y12, n);

  // x1 -> out[:,128:256], z2 (bf16) -> ws
  spmm_dual_kernel<<<(n + 3) / 4, 256, 0, stream>>>(y12, out + 128, z2,
                                                    offp, es, n);
  // x2 = A*z2 -> out[:,256:384]
  spmm_single_kernel<<<(n + 3) / 4, 256, 0, stream>>>(z2, out + 256,
                                                      offp, es, n);
}